// Round 11
// baseline (151.397 us; speedup 1.0000x reference)
//
#include <hip/hip_runtime.h>

typedef float floatx4 __attribute__((ext_vector_type(4)));
typedef int intx4 __attribute__((ext_vector_type(4)));
typedef int intx8 __attribute__((ext_vector_type(8)));
typedef __attribute__((address_space(1))) const void gvoid;
typedef __attribute__((address_space(3))) void svoid;

#define SCALE_POS 2.0f
#define SCALE_NEG 40.0f
#define THRESH 0.5f
#define MARGIN 0.1f
#define EPSV 1e-5f

// ---- kernel 1: fp32 -> fp8 e4m3 (OCP, RNE via HW cvt) + out zero ----
__global__ void k_init(const float* __restrict__ feats,
                       unsigned char* __restrict__ f8,
                       float* __restrict__ out,
                       int total4) {
    int i = blockIdx.x * blockDim.x + threadIdx.x;
    if (i < total4) {
        float4 v = ((const float4*)feats)[i];
        int w = 0;
        w = __builtin_amdgcn_cvt_pk_fp8_f32(v.x, v.y, w, false);  // bytes 0,1
        w = __builtin_amdgcn_cvt_pk_fp8_f32(v.z, v.w, w, true);   // bytes 2,3
        ((int*)f8)[i] = w;
    }
    if (i == 0) out[0] = 0.f;
}

// =====================================================================
// R27: NO simh. The 17MB-write + 17MB-read sim matrix (40% of total
// HBM round-trip bytes; total time fits bytes/0.65TB/s across R19-R26)
// is replaced by recomputing the GEMM in pass B from the L3-resident
// 4MB f8. No grid sync (R22's regression was the spin, not the math).
//
// kernel 2a (pass A): GEMM -> stat partials ONLY (R26 verbatim minus
// the simh store). [B][64] transposed partial layout.
// =====================================================================
__global__ void __launch_bounds__(256, 4)
k_gemmA(const unsigned char* __restrict__ f8,
        const int* __restrict__ labels,
        float* __restrict__ pmin,     // [B][64] partial min-pos
        float* __restrict__ pmax,     // [B][64] partial max-neg
        int D, int nb) {
    __shared__ __align__(16) unsigned char As[128 * 128];  // 16 KB
    __shared__ __align__(16) unsigned char Bs[128 * 128];  // 16 KB
    __shared__ int labR[128], labC[128];

    const int bid0 = blockIdx.x;
    const int t = (bid0 & 7) * 66 + (bid0 >> 3);   // 528 = 8 XCDs x 66
    int rb = 0, rem = t;
    while (rem >= nb - rb) { rem -= nb - rb; ++rb; }
    const int cb = rb + rem;
    const int rowBase = rb * 128;
    const int colBase = cb * 128;

    const int tid = threadIdx.x;        // 0..255
    const int lane = tid & 63;
    const int wave = tid >> 6;          // 0..3
    const int wr = wave >> 1;
    const int wc = wave & 1;
    const int q = lane >> 4;
    const int cIn = lane & 15;

    if (tid < 128) labR[tid] = labels[rowBase + tid];
    else           labC[tid - 128] = labels[colBase + (tid - 128)];

    const int subrow = lane >> 3;
    const int swz = (lane & 7) ^ subrow;
    const unsigned char* gP[8];
    unsigned char* lP[8];
#pragma unroll
    for (int j = 0; j < 8; ++j) {
        const int c = wave * 8 + j;
        const int grow = (c < 16) ? (rowBase + c * 8 + subrow)
                                  : (colBase + (c - 16) * 8 + subrow);
        gP[j] = f8 + (size_t)grow * D + swz * 16;
        lP[j] = ((c < 16) ? (As + c * 1024) : (Bs + (c - 16) * 1024)) + lane * 16;
    }

    int aOff0[4], aOff1[4], bOff0[4], bOff1[4];
#pragma unroll
    for (int i = 0; i < 4; ++i) {
        const int rA = wr * 64 + i * 16 + cIn;
        aOff0[i] = rA * 128 + ((2 * q) ^ (rA & 7)) * 16;
        aOff1[i] = rA * 128 + ((2 * q + 1) ^ (rA & 7)) * 16;
        const int rB = wc * 64 + i * 16 + cIn;
        bOff0[i] = rB * 128 + ((2 * q) ^ (rB & 7)) * 16;
        bOff1[i] = rB * 128 + ((2 * q + 1) ^ (rB & 7)) * 16;
    }

    floatx4 acc[4][4] = {};

    const int KT = D >> 7;
    for (int kt = 0; kt < KT; ++kt) {
        const int kOff = kt * 128;
        __syncthreads();
#pragma unroll
        for (int j = 0; j < 8; ++j)
            __builtin_amdgcn_global_load_lds((gvoid*)(gP[j] + kOff), (svoid*)lP[j], 16, 0, 0);
        __syncthreads();

        intx8 a[4], b[4];
#pragma unroll
        for (int i = 0; i < 4; ++i) {
            intx4 lo = *(const intx4*)(As + aOff0[i]);
            intx4 hi = *(const intx4*)(As + aOff1[i]);
            a[i] = __builtin_shufflevector(lo, hi, 0, 1, 2, 3, 4, 5, 6, 7);
        }
#pragma unroll
        for (int i = 0; i < 4; ++i) {
            intx4 lo = *(const intx4*)(Bs + bOff0[i]);
            intx4 hi = *(const intx4*)(Bs + bOff1[i]);
            b[i] = __builtin_shufflevector(lo, hi, 0, 1, 2, 3, 4, 5, 6, 7);
        }
#pragma unroll
        for (int i = 0; i < 4; ++i)
#pragma unroll
            for (int j2 = 0; j2 < 4; ++j2)
                acc[i][j2] = __builtin_amdgcn_mfma_scale_f32_16x16x128_f8f6f4(
                    a[i], b[j2], acc[i][j2], 0, 0,
                    0, 0x7f7f7f7f, 0, 0x7f7f7f7f);
    }

    int rLabv[16];
#pragma unroll
    for (int mi = 0; mi < 4; ++mi)
#pragma unroll
        for (int rr = 0; rr < 4; ++rr)
            rLabv[mi * 4 + rr] = labR[wr * 64 + mi * 16 + q * 4 + rr];
    int cLabv[4];
#pragma unroll
    for (int ni = 0; ni < 4; ++ni)
        cLabv[ni] = labC[wc * 64 + ni * 16 + cIn];

    // ---- row stats partials: pmin[r][2*cb+wc] ----
    {
        const int slotR = 2 * cb + wc;
#pragma unroll
        for (int mi = 0; mi < 4; ++mi)
#pragma unroll
            for (int rr = 0; rr < 4; ++rr) {
                const int rLoc = wr * 64 + mi * 16 + q * 4 + rr;
                const int rLab = rLabv[mi * 4 + rr];
                float vmin = 1e30f, vmax = -1e30f;
#pragma unroll
                for (int ni = 0; ni < 4; ++ni) {
                    float s = acc[mi][ni][rr];
                    if (rLab == cLabv[ni]) {
                        if (s < 1.0f - EPSV) vmin = fminf(vmin, s);
                    } else {
                        vmax = fmaxf(vmax, s);
                    }
                }
#pragma unroll
                for (int off = 8; off; off >>= 1) {
                    vmin = fminf(vmin, __shfl_xor(vmin, off, 16));
                    vmax = fmaxf(vmax, __shfl_xor(vmax, off, 16));
                }
                if (cIn == 0) {
                    pmin[(size_t)(rowBase + rLoc) * 64 + slotR] = vmin;
                    pmax[(size_t)(rowBase + rLoc) * 64 + slotR] = vmax;
                }
            }
    }

    // ---- col stats partials via symmetry (off-diag): pmin[c][2*rb+wr] ----
    if (rb != cb) {
        const int slotC = 2 * rb + wr;
#pragma unroll
        for (int ni = 0; ni < 4; ++ni) {
            const int cLab = cLabv[ni];
            float vmin = 1e30f, vmax = -1e30f;
#pragma unroll
            for (int mi = 0; mi < 4; ++mi)
#pragma unroll
                for (int rr = 0; rr < 4; ++rr) {
                    float s = acc[mi][ni][rr];
                    if (rLabv[mi * 4 + rr] == cLab) {
                        if (s < 1.0f - EPSV) vmin = fminf(vmin, s);
                    } else {
                        vmax = fmaxf(vmax, s);
                    }
                }
            vmin = fminf(vmin, __shfl_xor(vmin, 16, 64));
            vmin = fminf(vmin, __shfl_xor(vmin, 32, 64));
            vmax = fmaxf(vmax, __shfl_xor(vmax, 16, 64));
            vmax = fmaxf(vmax, __shfl_xor(vmax, 32, 64));
            if (q == 0) {
                const int cLoc = wc * 64 + ni * 16 + cIn;
                pmin[(size_t)(colBase + cLoc) * 64 + slotC] = vmin;
                pmax[(size_t)(colBase + cLoc) * 64 + slotC] = vmax;
            }
        }
    }
}

// =====================================================================
// kernel 2b (pass B): gate prologue (R26 contiguous [B][64] reads,
// loaded to LDS BEFORE the K-loop so it hides under staging) ->
// recompute GEMM (same f8, L3-resident; bit-identical acc) ->
// gated exp sums from fp32 acc (R22 phase-4 body) -> psP/psN [B][64].
// =====================================================================
__global__ void __launch_bounds__(256, 4)
k_gemmB(const unsigned char* __restrict__ f8,
        const int* __restrict__ labels,
        const float* __restrict__ pmin,
        const float* __restrict__ pmax,
        float* __restrict__ psP,      // [B][64]
        float* __restrict__ psN,      // [B][64]
        int D, int nb) {
    __shared__ __align__(16) unsigned char As[128 * 128];  // 16 KB
    __shared__ __align__(16) unsigned char Bs[128 * 128];  // 16 KB
    __shared__ int labR[128], labC[128];
    __shared__ float gNR[128], gPR[128], gNC[128], gPC[128];

    const int bid0 = blockIdx.x;
    const int t = (bid0 & 7) * 66 + (bid0 >> 3);
    int rb = 0, rem = t;
    while (rem >= nb - rb) { rem -= nb - rb; ++rb; }
    const int cb = rb + rem;
    const int rowBase = rb * 128;
    const int colBase = cb * 128;

    const int tid = threadIdx.x;
    const int lane = tid & 63;
    const int wave = tid >> 6;
    const int wr = wave >> 1;
    const int wc = wave & 1;
    const int q = lane >> 4;
    const int cIn = lane & 15;

    // ---- gate prologue: contiguous 256B per thread (R26-verified) ----
    {
        const int j = tid & 127;
        const int base = (tid < 128) ? (rowBase + j) : (colBase + j);
        const floatx4* pm = (const floatx4*)(pmin + (size_t)base * 64);
        const floatx4* px = (const floatx4*)(pmax + (size_t)base * 64);
        float mn = 1e30f, mx = -1e30f;
#pragma unroll
        for (int k = 0; k < 16; ++k) {
            floatx4 a = pm[k];
            floatx4 b = px[k];
            mn = fminf(mn, fminf(fminf(a[0], a[1]), fminf(a[2], a[3])));
            mx = fmaxf(mx, fmaxf(fmaxf(b[0], b[1]), fmaxf(b[2], b[3])));
        }
        if (tid < 128) {
            labR[j] = labels[rowBase + j];
            gNR[j] = mn - MARGIN;       // neg kept if s > gNR
            gPR[j] = mx + MARGIN;       // pos kept if s < gPR
        } else {
            labC[j] = labels[colBase + j];
            gNC[j] = mn - MARGIN;
            gPC[j] = mx + MARGIN;
        }
    }
    // (K-loop barriers provide the sync before any LDS gate reads)

    const int subrow = lane >> 3;
    const int swz = (lane & 7) ^ subrow;
    const unsigned char* gP[8];
    unsigned char* lP[8];
#pragma unroll
    for (int j = 0; j < 8; ++j) {
        const int c = wave * 8 + j;
        const int grow = (c < 16) ? (rowBase + c * 8 + subrow)
                                  : (colBase + (c - 16) * 8 + subrow);
        gP[j] = f8 + (size_t)grow * D + swz * 16;
        lP[j] = ((c < 16) ? (As + c * 1024) : (Bs + (c - 16) * 1024)) + lane * 16;
    }

    int aOff0[4], aOff1[4], bOff0[4], bOff1[4];
#pragma unroll
    for (int i = 0; i < 4; ++i) {
        const int rA = wr * 64 + i * 16 + cIn;
        aOff0[i] = rA * 128 + ((2 * q) ^ (rA & 7)) * 16;
        aOff1[i] = rA * 128 + ((2 * q + 1) ^ (rA & 7)) * 16;
        const int rB = wc * 64 + i * 16 + cIn;
        bOff0[i] = rB * 128 + ((2 * q) ^ (rB & 7)) * 16;
        bOff1[i] = rB * 128 + ((2 * q + 1) ^ (rB & 7)) * 16;
    }

    floatx4 acc[4][4] = {};

    const int KT = D >> 7;
    for (int kt = 0; kt < KT; ++kt) {
        const int kOff = kt * 128;
        __syncthreads();
#pragma unroll
        for (int j = 0; j < 8; ++j)
            __builtin_amdgcn_global_load_lds((gvoid*)(gP[j] + kOff), (svoid*)lP[j], 16, 0, 0);
        __syncthreads();

        intx8 a[4], b[4];
#pragma unroll
        for (int i = 0; i < 4; ++i) {
            intx4 lo = *(const intx4*)(As + aOff0[i]);
            intx4 hi = *(const intx4*)(As + aOff1[i]);
            a[i] = __builtin_shufflevector(lo, hi, 0, 1, 2, 3, 4, 5, 6, 7);
        }
#pragma unroll
        for (int i = 0; i < 4; ++i) {
            intx4 lo = *(const intx4*)(Bs + bOff0[i]);
            intx4 hi = *(const intx4*)(Bs + bOff1[i]);
            b[i] = __builtin_shufflevector(lo, hi, 0, 1, 2, 3, 4, 5, 6, 7);
        }
#pragma unroll
        for (int i = 0; i < 4; ++i)
#pragma unroll
            for (int j2 = 0; j2 < 4; ++j2)
                acc[i][j2] = __builtin_amdgcn_mfma_scale_f32_16x16x128_f8f6f4(
                    a[i], b[j2], acc[i][j2], 0, 0,
                    0, 0x7f7f7f7f, 0, 0x7f7f7f7f);
    }

    int rLabv[16];
#pragma unroll
    for (int mi = 0; mi < 4; ++mi)
#pragma unroll
        for (int rr = 0; rr < 4; ++rr)
            rLabv[mi * 4 + rr] = labR[wr * 64 + mi * 16 + q * 4 + rr];
    int cLabv[4];
    float gNCv[4], gPCv[4];
#pragma unroll
    for (int ni = 0; ni < 4; ++ni) {
        const int j = wc * 64 + ni * 16 + cIn;
        cLabv[ni] = labC[j];
        gNCv[ni] = gNC[j];
        gPCv[ni] = gPC[j];
    }

    const bool offd = (rb != cb);
    float cps[4] = {}, cns[4] = {};
    const int slotR = 2 * cb + wc;

#pragma unroll
    for (int mi = 0; mi < 4; ++mi)
#pragma unroll
        for (int rr = 0; rr < 4; ++rr) {
            const int rLoc = wr * 64 + mi * 16 + q * 4 + rr;
            const int rLab = rLabv[mi * 4 + rr];
            const float gn = gNR[rLoc];
            const float gp = gPR[rLoc];
            float rp = 0.f, rn = 0.f;
#pragma unroll
            for (int ni = 0; ni < 4; ++ni) {
                const float s = acc[mi][ni][rr];
                if (rLab == cLabv[ni]) {
                    if (s < 1.0f - EPSV) {
                        float ev = __expf(-SCALE_POS * (s - THRESH));
                        if (s < gp) rp += ev;
                        if (offd && s < gPCv[ni]) cps[ni] += ev;
                    }
                } else {
                    float ev = __expf(SCALE_NEG * (s - THRESH));
                    if (s > gn) rn += ev;
                    if (offd && s > gNCv[ni]) cns[ni] += ev;
                }
            }
#pragma unroll
            for (int off = 8; off; off >>= 1) {
                rp += __shfl_xor(rp, off, 16);
                rn += __shfl_xor(rn, off, 16);
            }
            if (cIn == 0) {
                psP[(size_t)(rowBase + rLoc) * 64 + slotR] = rp;
                psN[(size_t)(rowBase + rLoc) * 64 + slotR] = rn;
            }
        }
    if (offd) {
        const int slotC = 2 * rb + wr;
#pragma unroll
        for (int ni = 0; ni < 4; ++ni) {
            cps[ni] += __shfl_xor(cps[ni], 16, 64);
            cps[ni] += __shfl_xor(cps[ni], 32, 64);
            cns[ni] += __shfl_xor(cns[ni], 16, 64);
            cns[ni] += __shfl_xor(cns[ni], 32, 64);
            if (q == 0) {
                const int cLoc = wc * 64 + ni * 16 + cIn;
                psP[(size_t)(colBase + cLoc) * 64 + slotC] = cps[ni];
                psN[(size_t)(colBase + cLoc) * 64 + slotC] = cns[ni];
            }
        }
    }
}

// =====================================================================
// kernel 3: final reduce -> out[0] (16 blocks, one atomicAdd each).
// [B][64]: each thread sums 64 consecutive floats per array.
// =====================================================================
__global__ void __launch_bounds__(256)
k_final(const float* __restrict__ psP, const float* __restrict__ psN,
        float* __restrict__ out, int B) {
    __shared__ float red[4];
    const int r = blockIdx.x * 256 + threadIdx.x;
    const floatx4* pp = (const floatx4*)(psP + (size_t)r * 64);
    const floatx4* pn = (const floatx4*)(psN + (size_t)r * 64);
    float P = 0.f, N = 0.f;
#pragma unroll
    for (int k = 0; k < 16; ++k) {
        floatx4 a = pp[k];
        P += (a[0] + a[1]) + (a[2] + a[3]);
        floatx4 b = pn[k];
        N += (b[0] + b[1]) + (b[2] + b[3]);
    }
    float a = (P > 0.f && N > 0.f)
                  ? log1pf(P) * (1.0f / SCALE_POS) + log1pf(N) * (1.0f / SCALE_NEG)
                  : 0.f;
#pragma unroll
    for (int off = 32; off; off >>= 1) a += __shfl_down(a, off, 64);
    const int tid = threadIdx.x;
    if ((tid & 63) == 0) red[tid >> 6] = a;
    __syncthreads();
    if (tid == 0)
        atomicAdd(out, (red[0] + red[1] + red[2] + red[3]) / (float)B);
}

extern "C" void kernel_launch(void* const* d_in, const int* in_sizes, int n_in,
                              void* d_out, int out_size, void* d_ws, size_t ws_size,
                              hipStream_t stream) {
    const float* feats = (const float*)d_in[0];
    const int* labels = (const int*)d_in[1];
    const int B = in_sizes[1];            // 4096
    const int D = in_sizes[0] / B;        // 1024
    const int nb = B / 128;               // 32
    const int NT = nb * (nb + 1) / 2;     // 528
    const int total4 = B * D / 4;

    char* ws = (char*)d_ws;
    unsigned char* f8 = (unsigned char*)ws;
    size_t off = (size_t)B * D;           // 4 MB fp8
    float* pmin = (float*)(ws + off); off += (size_t)64 * B * 4;   // 1 MB, [B][64]
    float* pmax = (float*)(ws + off); off += (size_t)64 * B * 4;   // 1 MB, [B][64]
    float* psP  = (float*)(ws + off); off += (size_t)64 * B * 4;   // 1 MB, [B][64]
    float* psN  = (float*)(ws + off); off += (size_t)64 * B * 4;   // 1 MB, [B][64]
    float* outp = (float*)d_out;

    k_init<<<(total4 + 255) / 256, 256, 0, stream>>>(feats, f8, outp, total4);

    // pass A: GEMM -> stat partials only (no simh)
    k_gemmA<<<NT, 256, 0, stream>>>(f8, labels, pmin, pmax, D, nb);

    // pass B: gates -> recompute GEMM -> gated exp sums from fp32 acc
    k_gemmB<<<NT, 256, 0, stream>>>(f8, labels, pmin, pmax, psP, psN, D, nb);

    // final: 16 blocks, one atomic each
    k_final<<<B / 256, 256, 0, stream>>>(psP, psN, outp, B);
}